// Round 1
// baseline (2342.903 us; speedup 1.0000x reference)
//
#include <hip/hip_runtime.h>
#include <cstdint>
#include <cstddef>

#define S 108
#define NEMIT 126
#define NCOD 16
#define T_LEN 2048
#define N_BATCH 256
#define MAXC 18   // max column in-degree of A is 18 (col 52)

// ---- emission-structure enumeration (mirrors _emission_structure) ----
// sym codes: 0..3 = A,C,G,T ; 4 = 'N' (expands to {0,1,2,3}) ; 5 = 'X' marker
__device__ __forceinline__ int maskFor(int sym, int add4) {
  int m = (sym == 4) ? 0xF : (1 << sym);
  if (add4) m |= 0x10;           // literal kmer digit 4 ("pad") allowed
  return m;
}

// Iterates accepted kmer ids in EXACT Python product() order:
// x0 slowest, x2 fastest; each allowed set ascending (CODE order then 4).
// Rejection rule: a literal 4 in position 1 after a non-4 in position 0.
template <typename F>
__device__ __forceinline__ void enumCall(int s0, int s1, int s2, int xmust, F&& f) {
  int m0 = maskFor(s0, xmust < 2 ? 1 : 0);
  int m1 = maskFor(s1, xmust < 1 ? 1 : 0);
  int m2 = maskFor(s2, 0);
  for (int x0 = 0; x0 < 5; x0++) {
    if (!((m0 >> x0) & 1)) continue;
    for (int x1 = 0; x1 < 5; x1++) {
      if (!((m1 >> x1) & 1)) continue;
      if (x0 != 4 && x1 == 4) continue;   // 4s must be a prefix among first two
      for (int x2 = 0; x2 < 5; x2++) {
        if (!((m2 >> x2) & 1)) continue;
        f(x0 * 25 + x1 * 5 + x2);
      }
    }
  }
}

__device__ __forceinline__ float blockReduceSum(float v, float* sbuf, int tid) {
#pragma unroll
  for (int o = 32; o >= 1; o >>= 1) v += __shfl_down(v, o, 64);
  if ((tid & 63) == 0) sbuf[tid >> 6] = v;
  __syncthreads();
  return sbuf[0] + sbuf[1];
}

__global__ __launch_bounds__(128, 1) void hmm_fwd_kernel(
    const int* __restrict__ inp, const float* __restrict__ w,
    const float* __restrict__ ek, const float* __restrict__ ik,
    float* __restrict__ out) {
  __shared__ __align__(16) float Bt_lds[NEMIT * S];  // Bt[col*S + state], 54.4 KB
  __shared__ float alpha[128];
  __shared__ float sbuf[2];
  __shared__ float pi_lds[S];
  __shared__ short arow[288], acol[288];
  __shared__ float avalS[288];
  __shared__ int s_ne, s_ncalls;
  __shared__ unsigned char cst[116], cs0[116], cs1[116], cs2[116], cxm[116], ctr[116];
  __shared__ int kOffL[116];

  const int tid = threadIdx.x;

  // ---------- phase 0: zero Bt; serial builders on threads 0/1/2 ----------
  for (int i = tid; i < NEMIT * S; i += 128) Bt_lds[i] = 0.f;

  if (tid == 0) {
    // call table of _emission_structure(16), syms already reduced to last-3
    int c = 0;
    auto CC = [&](int st, int a, int b, int d, int xm, int tr) {
      cst[c] = (unsigned char)st; cs0[c] = (unsigned char)a; cs1[c] = (unsigned char)b;
      cs2[c] = (unsigned char)d; cxm[c] = (unsigned char)xm; ctr[c] = (unsigned char)tr; c++;
    };
    CC(0, 4, 4, 4, 0, 1);            // 'N'    -> N N N, xmust 0
    CC(1, 4, 4, 0, 0, 1);            // 'A'    -> N N A
    CC(2, 4, 0, 3, 0, 1);            // 'AT'   -> N A T
    CC(3, 0, 3, 2, 2, 0);            // 'ATG'  (non-trainable)
    CC(4, 3, 2, 4, 2, 1);            // 'ATGN' -> T G N
    CC(5, 2, 4, 4, 2, 1);            // 'ATGNN'-> G N N
    for (int s = 6; s <= 51; s++) CC(s, 4, 4, 4, 2, 1);
    CC(52, 4, 4, 3, 2, 1);           // 'T'  -> N N T
    CC(53, 4, 3, 0, 2, 1);           // 'TA' -> N T A
    CC(53, 4, 3, 2, 2, 1);           // 'TG' -> N T G
    CC(54, 3, 0, 0, 2, 0);           // 'TAA'
    CC(54, 3, 0, 2, 2, 0);           // 'TAG'
    CC(54, 3, 2, 0, 2, 0);           // 'TGA'
    CC(55, 4, 4, 4, 2, 1);
    for (int s = 56; s <= 106; s++) CC(s, 4, 4, 4, 2, 1);
    CC(107, 5, 5, 5, 2, 1);          // 'X' special (col 125, widx -1)
    s_ncalls = c;                    // = 111
  }
  if (tid == 1) {
    // _build_A(w, 16) entry list (280 entries)
    int ne = 0;
    auto AD = [&](int r, int c2, float v) {
      arow[ne] = (short)r; acol[ne] = (short)c2; avalS[ne] = v; ne++;
    };
    float w0 = w[0];
    AD(0, 0, 1.f - w0); AD(0, 1, w0); AD(1, 2, 1.f); AD(2, 3, 1.f);
    int k = 1;
    for (int i = 0; i < NCOD; i++) AD(3 + 3 * i, 4 + 3 * i, w[k + i]);
    k += NCOD;                                            // k = 17
    for (int i = 0; i < NCOD; i++) AD(4 + 3 * i, 5 + 3 * i, 1.f);
    for (int i = 0; i < NCOD; i++) AD(5 + 3 * i, 6 + 3 * i, 1.f);
    for (int i = 0; i <= NCOD; i++) AD(3 + 3 * i, 56 + 3 * i, w[k + i]);
    k += NCOD + 1;                                        // k = 34
    AD(51, 52, w[k]); k += 1;                             // k = 35
    for (int i = 0; i <= NCOD; i++) AD(56 + 3 * i, 57 + 3 * i, 1.f);
    for (int i = 0; i <= NCOD; i++) AD(57 + 3 * i, 58 + 3 * i, 1.f);
    for (int i = 0; i <= NCOD; i++) AD(58 + 3 * i, 4 + 3 * i, w[k + i]);
    for (int i = 0; i <= NCOD; i++) AD(58 + 3 * i, 56 + 3 * i, 1.f - w[k + i]);
    k += NCOD + 1;                                        // k = 52
    float wk = w[k];
    float sgnw = (wk > 0.f) ? 1.f : ((wk < 0.f) ? -1.f : 0.f);
    for (int a = 0; a < NCOD; a++)
      for (int jj = a + 1; jj <= NCOD; jj++) {
        int e = jj - a + 1;                               // exponent
        float sgn = (e & 1) ? sgnw : 1.f;
        AD(3 + 3 * a, 4 + 3 * jj, 1.f - sgn * powf(fabsf(wk), (float)e));
      }
    AD(52, 53, 1.f); AD(53, 54, 1.f); AD(54, 55, 1.f);
    AD(55, 55, 1.f); AD(55, 107, 1.f); AD(107, 107, 1.f);
    s_ne = ne;                                            // = 280
  }
  if (tid == 2) {
    // pi = softmax(init_kernel)
    float m = -1e30f;
    for (int i = 0; i < S; i++) m = fmaxf(m, ik[i]);
    float z = 0.f;
    for (int i = 0; i < S; i++) z += expf(ik[i] - m);
    for (int i = 0; i < S; i++) pi_lds[i] = expf(ik[i] - m) / z;
  }
  __syncthreads();

  const int ncalls = s_ncalls;
  const int ne = s_ne;

  // ---------- phase 1: per-call trainable-weight offsets; A row-softmax ----------
  if (tid < ncalls) {
    int ko = 0;
    for (int c = 0; c < tid; c++) {
      if (ctr[c] && cs0[c] != 5) {
        int cnt = 0;
        enumCall(cs0[c], cs1[c], cs2[c], cxm[c], [&](int) { cnt++; });
        ko += cnt;
      }
    }
    kOffL[tid] = ko;
  }
  if (tid < S) {  // row-softmax of A's sparse entries (in-place on avalS)
    float m = -1e30f;
    for (int e = 0; e < ne; e++)
      if (arow[e] == tid) m = fmaxf(m, avalS[e]);
    float z = 0.f;
    for (int e = 0; e < ne; e++)
      if (arow[e] == tid) z += expf(avalS[e] - m);
    for (int e = 0; e < ne; e++)
      if (arow[e] == tid) avalS[e] = expf(avalS[e] - m) / z;
  }
  __syncthreads();

  // ---------- phase 2: B row-softmax -> Bt_lds; CSC of A into registers ----------
  if (tid < S) {
    float m = -1e30f;
    for (int c = 0; c < ncalls; c++) {
      if (cst[c] != tid) continue;
      if (cs0[c] == 5) { m = fmaxf(m, 1.f); continue; }
      if (ctr[c]) {
        int ko = kOffL[c];
        enumCall(cs0[c], cs1[c], cs2[c], cxm[c], [&](int) { m = fmaxf(m, ek[ko++]); });
      } else {
        m = fmaxf(m, 1.f);
      }
    }
    float z = 0.f;
    for (int c = 0; c < ncalls; c++) {
      if (cst[c] != tid) continue;
      if (cs0[c] == 5) { z += expf(1.f - m); continue; }
      if (ctr[c]) {
        int ko = kOffL[c];
        enumCall(cs0[c], cs1[c], cs2[c], cxm[c], [&](int) { z += expf(ek[ko++] - m); });
      } else {
        enumCall(cs0[c], cs1[c], cs2[c], cxm[c], [&](int) { z += expf(1.f - m); });
      }
    }
    for (int c = 0; c < ncalls; c++) {
      if (cst[c] != tid) continue;
      if (cs0[c] == 5) { Bt_lds[125 * S + tid] = expf(1.f - m) / z; continue; }
      if (ctr[c]) {
        int ko = kOffL[c];
        enumCall(cs0[c], cs1[c], cs2[c], cxm[c],
                 [&](int col) { Bt_lds[col * S + tid] = expf(ek[ko++] - m) / z; });
      } else {
        enumCall(cs0[c], cs1[c], cs2[c], cxm[c],
                 [&](int col) { Bt_lds[col * S + tid] = expf(1.f - m) / z; });
      }
    }
  }

  // CSC column of A for this thread's state, zero-padded to MAXC.
  // Static-index writes only (unrolled compare chain) so arrays stay in VGPRs.
  float av[MAXC];
  int ai[MAXC];
#pragma unroll
  for (int e = 0; e < MAXC; e++) { av[e] = 0.f; ai[e] = 0; }
  {
    int cnt = 0;
    for (int e = 0; e < ne; e++) {
      if ((int)acol[e] == tid) {
#pragma unroll
        for (int slot = 0; slot < MAXC; slot++)
          if (cnt == slot) { ai[slot] = (int)arow[e]; av[slot] = avalS[e]; }
        cnt++;
      }
    }
  }
  const float pj = (tid < S) ? pi_lds[tid] : 0.f;
  __syncthreads();   // Bt_lds ready

  // ---------- phase 3: the forward scan ----------
  const int* seq = inp + (size_t)blockIdx.x * T_LEN;
  float* ob = out + (size_t)blockIdx.x * T_LEN * S;

  int et = seq[0];
  float v = (tid < S) ? pj * Bt_lds[et * S + tid] : 0.f;
  float tot = blockReduceSum(v, sbuf, tid);
  float a0 = v / tot;
  if (tid < S) { alpha[tid] = a0; ob[tid] = a0; }
  __syncthreads();

  int etn = seq[1];
  for (int t = 1; t < T_LEN; t++) {
    const int ecur = etn;
    if (t + 1 < T_LEN) etn = seq[t + 1];   // prefetch next symbol (uniform s_load)
    float acc = 0.f;
#pragma unroll
    for (int e = 0; e < MAXC; e++) acc += alpha[ai[e]] * av[e];
    const int jj = (tid < S) ? tid : 0;
    acc *= Bt_lds[ecur * S + jj];
    const float tt = blockReduceSum(acc, sbuf, tid);   // internal barrier also
                                                       // fences alpha reads
    const float an = acc / tt;
    if (tid < S) { alpha[tid] = an; ob[(size_t)t * S + tid] = an; }
    __syncthreads();
  }
}

extern "C" void kernel_launch(void* const* d_in, const int* in_sizes, int n_in,
                              void* d_out, int out_size, void* d_ws, size_t ws_size,
                              hipStream_t stream) {
  const int* inp = (const int*)d_in[0];        // [256, 2048] int32 kmer ids
  const float* w = (const float*)d_in[1];      // transition_kernel [53]
  const float* ek = (const float*)d_in[2];     // emission_kernel [108*216]
  const float* ik = (const float*)d_in[3];     // init_kernel [108]
  float* out = (float*)d_out;                  // [256, 2048, 108] f32
  (void)d_ws; (void)ws_size; (void)in_sizes; (void)n_in; (void)out_size;
  hmm_fwd_kernel<<<N_BATCH, 128, 0, stream>>>(inp, w, ek, ik, out);
}